// Round 11
// baseline (104.396 us; speedup 1.0000x reference)
//
#include <hip/hip_runtime.h>

// AttentionNet N=128, a1=a2=64, f=2 — R11: stall-overlap via independent
// co-resident blocks. Grid 4N=512 x 512 threads (8 waves): each block = one
// QUARTER (16 rows) of one n, full k. 2 blocks/CU, paired blocks are
// different-n (n = blockIdx>>2) -> barrier/spin stalls of one block overlap
// with issue of the other. Protocol (encoded m+2.0 global slots, poll-all-64)
// and inner loop (b128 p-loads, readlane q, pairwise rcp, DPP reductions)
// unchanged from R10.

constexpr int A   = 64;
constexpr int PAD = 68;   // floats; 272 B row stride: 16B-aligned
constexpr float L2E  = 1.4426950408889634f;
constexpr float EPSF = 1e-6f;

__device__ __forceinline__ float bcast(float v, int srcLane) {
    return __int_as_float(__builtin_amdgcn_readlane(__float_as_int(v), srcLane));
}
__device__ __forceinline__ float rcpf(float v) { return __builtin_amdgcn_rcpf(v); }
__device__ __forceinline__ float ex2(float v)  { return __builtin_amdgcn_exp2f(v); }

// DPP wave64 reductions on the VALU pipe (identity 0 ok: values >= 0).
template <int CTRL>
__device__ __forceinline__ float upd_dpp(float src) {
    return __int_as_float(__builtin_amdgcn_update_dpp(
        0, __float_as_int(src), CTRL, 0xF, 0xF, true));
}
__device__ __forceinline__ float wave_sum64(float x) {
    x += upd_dpp<0x111>(x);
    x += upd_dpp<0x112>(x);
    x += upd_dpp<0x114>(x);
    x += upd_dpp<0x118>(x);
    x += upd_dpp<0x142>(x);   // row_bcast:15
    x += upd_dpp<0x143>(x);   // row_bcast:31
    return bcast(x, 63);
}
__device__ __forceinline__ float wave_max64(float x) {
    x = fmaxf(x, upd_dpp<0x111>(x));
    x = fmaxf(x, upd_dpp<0x112>(x));
    x = fmaxf(x, upd_dpp<0x114>(x));
    x = fmaxf(x, upd_dpp<0x118>(x));
    x = fmaxf(x, upd_dpp<0x142>(x));
    x = fmaxf(x, upd_dpp<0x143>(x));
    return bcast(x, 63);
}

// Reduce rows row0,row0+1 (lane <-> column j). lane0 writes LDS mbuf and the
// encoded global slot (m+2.0: sign 0, exp 128 -> self-validating vs poison).
__device__ __forceinline__ void att2q(const float* __restrict__ prow,
                                      const float* __restrict__ qL,
                                      int row0, int lane,
                                      float* __restrict__ mbuf,
                                      float* __restrict__ mg)
{
    const float qreg0 = qL[row0 * PAD + lane];
    const float qreg1 = qL[(row0 + 1) * PAD + lane];
    float acc0 = 0.f, acc1 = 0.f;
#pragma unroll 1
    for (int c = 0; c < 4; ++c) {
        float pk[16];                                    // 4x ds_read_b128
        *(float4*)(&pk[0])  = *(const float4*)(prow + c * 16 + 0);
        *(float4*)(&pk[4])  = *(const float4*)(prow + c * 16 + 4);
        *(float4*)(&pk[8])  = *(const float4*)(prow + c * 16 + 8);
        *(float4*)(&pk[12]) = *(const float4*)(prow + c * 16 + 12);
#pragma unroll
        for (int t = 0; t < 8; ++t) {                    // k-pairs, pairwise rcp
            const int k0 = c * 16 + 2 * t, k1 = k0 + 1;
            {
                float u0 = fmaf(pk[2 * t],     bcast(qreg0, k0), 1.0f);
                float u1 = fmaf(pk[2 * t + 1], bcast(qreg0, k1), 1.0f);
                acc0 = fmaf(u0 + u1, rcpf(u0 * u1), acc0);
            }
            {
                float u0 = fmaf(pk[2 * t],     bcast(qreg1, k0), 1.0f);
                float u1 = fmaf(pk[2 * t + 1], bcast(qreg1, k1), 1.0f);
                acc1 = fmaf(u0 + u1, rcpf(u0 * u1), acc1);
            }
        }
    }
    const float s0 = wave_sum64(acc0), m0 = wave_max64(acc0);
    const float s1 = wave_sum64(acc1), m1 = wave_max64(acc1);
    if (lane == 0) {
        float v0 = (s0 * (1.0f / 4096.0f)) / (m0 * (1.0f / 64.0f) + EPSF);
        float v1 = (s1 * (1.0f / 4096.0f)) / (m1 * (1.0f / 64.0f) + EPSF);
        mbuf[row0]     = v0;
        mbuf[row0 + 1] = v1;
        __hip_atomic_store(mg + row0,     v0 + 2.0f, __ATOMIC_RELAXED, __HIP_MEMORY_SCOPE_AGENT);
        __hip_atomic_store(mg + row0 + 1, v1 + 2.0f, __ATOMIC_RELAXED, __HIP_MEMORY_SCOPE_AGENT);
    }
}

__device__ __forceinline__ float softmax64(float m, float sharp, float th, bool last)
{
    float v = fmaxf(0.f, m * sharp + th);
    float mx = wave_max64(v);
    float e = __expf(v - mx);
    float s = wave_sum64(e);
    float r = e / s;
    if (!last) {
        float rm = wave_max64(r);
        r = r / (rm + EPSF);
    }
    return r;
}

// Wave-0 only: own quarter's m from LDS, rest via spin on encoded slots.
__device__ __forceinline__ float exch_soft(const float* __restrict__ mbuf,
                                           const float* __restrict__ mg,
                                           int qtr, int lane,
                                           float sharp, float th, bool last)
{
    float mv;
    if ((lane >> 4) == qtr) {
        mv = mbuf[lane];
    } else {
        const float* p = mg + lane;
        for (;;) {
            float f = __hip_atomic_load(p, __ATOMIC_RELAXED, __HIP_MEMORY_SCOPE_AGENT);
            unsigned u = __float_as_uint(f);
            if ((u >> 23) == 0x80u) { mv = f - 2.0f; break; }   // sign 0, exp 128
            __builtin_amdgcn_s_sleep(1);
        }
    }
    return softmax64(mv, sharp, th, last);
}

__global__ __launch_bounds__(512, 4)
void attn_qtr(const float* __restrict__ x,
              const float* __restrict__ fcW, const float* __restrict__ fcb,
              const float* __restrict__ p1W, const float* __restrict__ p1b,
              const float* __restrict__ p1s, const float* __restrict__ p1t,
              const float* __restrict__ p2W, const float* __restrict__ p2b,
              const float* __restrict__ p2s, const float* __restrict__ p2t,
              const float* __restrict__ oW,  const float* __restrict__ ob,
              const float* __restrict__ os,  const float* __restrict__ ot,
              float* __restrict__ mglob,     // [N][3][64]
              float* __restrict__ out)
{
    __shared__ __align__(16) float pL[A * PAD];
    __shared__ __align__(16) float qL[A * PAD];
    __shared__ float mbuf[A];
    __shared__ float v1buf[A], v2buf[A];

    const int tid = threadIdx.x, lane = tid & 63, wv = tid >> 6;
    const int n = blockIdx.x >> 2, qtr = blockIdx.x & 3;
    const int row0 = qtr * 16 + wv * 2;
    const int ti = tid >> 3, tj = (tid & 7) * 8;   // this thread: row ti, cols tj..tj+7
    float* mg = mglob + (size_t)n * 3 * A;

    // ---- x loaded once (8 elems/thread/channel); h0/h1 in registers ----
    const float4* x0v = (const float4*)(x + (size_t)n * 2 * A * A);
    const float4* x1v = x0v + (A * A / 4);
    const float4 a0 = x0v[2 * tid], a1 = x0v[2 * tid + 1];
    const float4 c0 = x1v[2 * tid], c1 = x1v[2 * tid + 1];
    const float w00 = fcW[0], w01 = fcW[1], w10 = fcW[2], w11 = fcW[3];
    const float b0 = fcb[0], b1 = fcb[1];
    const float xs0[8] = { a0.x, a0.y, a0.z, a0.w, a1.x, a1.y, a1.z, a1.w };
    const float xs1[8] = { c0.x, c0.y, c0.z, c0.w, c1.x, c1.y, c1.z, c1.w };
    float h0v[8], h1v[8];
#pragma unroll
    for (int t = 0; t < 8; ++t) {
        h0v[t] = fmaxf(0.f, w00 * xs0[t] + w01 * xs1[t] + b0);
        h1v[t] = fmaxf(0.f, w10 * xs0[t] + w11 * xs1[t] + b1);
    }

    // ======== stage B: X = h0 (row-major, float4 stores) ========
    {
        const float W0 = p1W[0], W1 = p1W[1], bb = p1b[0];
        float pv[8], qv[8];
#pragma unroll
        for (int t = 0; t < 8; ++t) {
            pv[t] = ex2(-L2E * (W0 * h0v[t] + bb));
            qv[t] = ex2(-L2E * (W1 * h0v[t]));
        }
        *(float4*)&pL[ti * PAD + tj]     = *(float4*)&pv[0];
        *(float4*)&pL[ti * PAD + tj + 4] = *(float4*)&pv[4];
        *(float4*)&qL[ti * PAD + tj]     = *(float4*)&qv[0];
        *(float4*)&qL[ti * PAD + tj + 4] = *(float4*)&qv[4];
    }
    __syncthreads();
    att2q(pL + lane * PAD, qL, row0, lane, mbuf, mg);
    __syncthreads();
    if (wv == 0) v1buf[lane] = exch_soft(mbuf, mg, qtr, lane, p1s[0], p1t[0], false);
    __syncthreads();

    // ======== stage C: X[r][k] = h1[k][r] * v1[k] (transposed scalar stores) ====
    {
        const float W0 = p2W[0], W1 = p2W[1], bb = p2b[0];
        const float sc = v1buf[ti];
#pragma unroll
        for (int t = 0; t < 8; ++t) {
            float hv = h1v[t] * sc;
            pL[(tj + t) * PAD + ti] = ex2(-L2E * (W0 * hv + bb));
            qL[(tj + t) * PAD + ti] = ex2(-L2E * (W1 * hv));
        }
    }
    __syncthreads();
    att2q(pL + lane * PAD, qL, row0, lane, mbuf, mg + A);
    __syncthreads();
    if (wv == 0) v2buf[lane] = exch_soft(mbuf, mg + A, qtr, lane, p2s[0], p2t[0], false);
    __syncthreads();

    // ======== stage D: X = h0 * v1[i] * v2[j] (row-major, float4 stores) ====
    {
        const float W0 = oW[0], W1 = oW[1], bb = ob[0];
        const float sc = v1buf[ti];
        float pv[8], qv[8];
#pragma unroll
        for (int t = 0; t < 8; ++t) {
            float hv = h0v[t] * sc * v2buf[tj + t];
            pv[t] = ex2(-L2E * (W0 * hv + bb));
            qv[t] = ex2(-L2E * (W1 * hv));
        }
        *(float4*)&pL[ti * PAD + tj]     = *(float4*)&pv[0];
        *(float4*)&pL[ti * PAD + tj + 4] = *(float4*)&pv[4];
        *(float4*)&qL[ti * PAD + tj]     = *(float4*)&qv[0];
        *(float4*)&qL[ti * PAD + tj + 4] = *(float4*)&qv[4];
    }
    __syncthreads();
    att2q(pL + lane * PAD, qL, row0, lane, mbuf, mg + 2 * A);
    __syncthreads();

    // ======== final softmax (is_last); each block writes its 16 outputs ====
    if (wv == 0) {
        float r = exch_soft(mbuf, mg + 2 * A, qtr, lane, os[0], ot[0], true);
        if ((lane >> 4) == qtr) out[(size_t)n * A + lane] = r;
    }
}

extern "C" void kernel_launch(void* const* d_in, const int* in_sizes, int n_in,
                              void* d_out, int out_size, void* d_ws, size_t ws_size,
                              hipStream_t stream)
{
    (void)n_in; (void)out_size; (void)ws_size;
    const float* x   = (const float*)d_in[0];
    const float* fcW = (const float*)d_in[1];
    const float* fcb = (const float*)d_in[2];
    const float* p1W = (const float*)d_in[3];
    const float* p1b = (const float*)d_in[4];
    const float* p1s = (const float*)d_in[5];
    const float* p1t = (const float*)d_in[6];
    const float* p2W = (const float*)d_in[7];
    const float* p2b = (const float*)d_in[8];
    const float* p2s = (const float*)d_in[9];
    const float* p2t = (const float*)d_in[10];
    const float* oW  = (const float*)d_in[11];
    const float* ob  = (const float*)d_in[12];
    const float* os  = (const float*)d_in[13];
    const float* ot  = (const float*)d_in[14];
    float* out = (float*)d_out;

    const int N = in_sizes[0] / (2 * A * A);   // 128
    float* mglob = (float*)d_ws;               // [N][3][64]

    attn_qtr<<<4 * N, 512, 0, stream>>>(x, fcW, fcb,
                                        p1W, p1b, p1s, p1t,
                                        p2W, p2b, p2s, p2t,
                                        oW, ob, os, ot, mglob, out);
}